// Round 7
// baseline (509.001 us; speedup 1.0000x reference)
//
#include <hip/hip_runtime.h>

#define TT 1024
#define BB 2048
#define K1 8
#define L2E2 2.8853900817779268f  // 2*log2(e)

// DPP helpers ----------------------------------------------------------------
template <int CTRL>
__device__ __forceinline__ float dpp_add(float x) {
  int y = __builtin_amdgcn_update_dpp(0, __float_as_int(x), CTRL, 0xF, 0xF, true);
  return x + __int_as_float(y);
}
// Sum within each aligned 16-lane row; result replicated in all 16 lanes.
__device__ __forceinline__ float sum16(float x) {
  x = dpp_add<0xB1>(x);   // quad_perm xor1
  x = dpp_add<0x4E>(x);   // quad_perm xor2
  x = dpp_add<0x141>(x);  // row_half_mirror
  x = dpp_add<0x140>(x);  // row_mirror
  return x;
}
// ROW_BCAST15: row r gets last lane of row r-1 (row0 -> 0).
__device__ __forceinline__ float bcast15(float x) {
  return __int_as_float(
      __builtin_amdgcn_update_dpp(0, __float_as_int(x), 0x142, 0xF, 0xF, true));
}
__device__ __forceinline__ float rdlane(float x, int l) {
  return __int_as_float(__builtin_amdgcn_readlane(__float_as_int(x), l));
}

// ---------------------------------------------------------------------------
// Fused kernel: RK4 scan (phase1) + estC head (former phase2) in one pass.
// ONE element per 64-lane wave, 2048 waves = 2 waves/SIMD (r5 winner).
// Rows: row0=NN1/A, row1=NN2/B, row2=NN3/C, row3=NN3dup/Cdup.
// RK4 stage: one eval stream, sum16, one bcast15 (row1<-P1, row2<-P2),
// one readlane (P3 -> row1):
//   row0: KA = -0.1A + (0.2-C1) + 0.1u - P1(own)
//   row1: KB = -0.1B + cbC - 3P2(own) + (5/3)P1(m1) + P3(rdlane)
//   row2: KC = -0.1C + ccC -  P3(own) +       P2(m1)
//   row3: dup of row2's state; K = -0.1C + ccC - P3 + P3(m1) = decay (unused)
// estC per 8-step chunk: A/B history broadcast via readlane (lanes 0/16),
// u history already lane-uniform; t<4 edge seeded from x0's z-part into a
// rolling 4-deep window. Each pass: lane h=lane&31 computes hidden unit h
// (dup on upper half); sum16 + bcast15 gives the 32-wide total on rows 1&3.
// Stores: lanes 0/16/32/48 write comps 0/1/2/3 of one 16B line (coalesced).
__global__ __launch_bounds__(256) void fused_kernel(
    const float* __restrict__ useq, const float* __restrict__ x0,
    const float* __restrict__ r1W0, const float* __restrict__ r1b0,
    const float* __restrict__ r1W1, const float* __restrict__ r1b1,
    const float* __restrict__ r2W0, const float* __restrict__ r2b0,
    const float* __restrict__ r2W1, const float* __restrict__ r2b1,
    const float* __restrict__ r3W0, const float* __restrict__ r3b0,
    const float* __restrict__ r3W1, const float* __restrict__ r3b1,
    const float* __restrict__ eW0, const float* __restrict__ eb0,
    const float* __restrict__ eW1, const float* __restrict__ eb1,
    float* __restrict__ out) {
  const int lane = threadIdx.x & 63;
  const int row = lane >> 4;
  const int j = lane & 15;
  const int e =
      __builtin_amdgcn_readfirstlane(blockIdx.x * 4 + (threadIdx.x >> 6));

  // RK4 per-lane weights (rows 2,3 share NN3).
  const float* W0p = (row == 0) ? r1W0 : (row == 1) ? r2W0 : r3W0;
  const float* b0p = (row == 0) ? r1b0 : (row == 1) ? r2b0 : r3b0;
  const float* W1p = (row == 0) ? r1W1 : (row == 1) ? r2W1 : r3W1;
  const float w0s = W0p[j] * L2E2;
  const float b0s = b0p[j] * L2E2;
  const float wn = -2.0f * W1p[j];

  // C_i = b1_i + sum_j W1_i[j]  (uniform, init-only).
  float C1 = r1b1[0], C2 = r2b1[0], C3 = r3b1[0];
  for (int q = 0; q < 16; ++q) {
    C1 += r1W1[q]; C2 += r2W1[q]; C3 += r3W1[q];
  }
  const float caC = 0.2f - C1;
  const float cbC = -1.0f / 6.0f + (5.0f / 3.0f) * C1 - 3.0f * C2 + C3;
  const float ccC = -1.0f / 6.0f + C2 - C3;

  // Per-lane combine coefficients.
  const float cstBase = (row == 0) ? caC : (row == 1) ? cbC : ccC;
  const float uco = (row == 0) ? 0.1f : 0.0f;
  const float aOwn = (row == 1) ? -3.0f : -1.0f;
  const float aM1 = (row == 0) ? 0.0f : (row == 1) ? (5.0f / 3.0f) : 1.0f;
  const float aR = (row == 1) ? 1.0f : 0.0f;

  float S = x0[e * 15 + ((row == 0) ? 0 : (row == 1) ? 1 : 2)];

  // estC per-lane weights: hidden unit h = lane & 31 (upper half duplicates).
  const int h = lane & 31;
  float ew0 = eW0[0 * 32 + h] * L2E2, ew1 = eW0[1 * 32 + h] * L2E2;
  float ew2 = eW0[2 * 32 + h] * L2E2, ew3 = eW0[3 * 32 + h] * L2E2;
  float ew4 = eW0[4 * 32 + h] * L2E2, ew5 = eW0[5 * 32 + h] * L2E2;
  float ew6 = eW0[6 * 32 + h] * L2E2, ew7 = eW0[7 * 32 + h] * L2E2;
  float ew8 = eW0[8 * 32 + h] * L2E2, ew9 = eW0[9 * 32 + h] * L2E2;
  float ew10 = eW0[10 * 32 + h] * L2E2, ew11 = eW0[11 * 32 + h] * L2E2;
  const float ebv = eb0[h] * L2E2;
  const float ewn = -2.0f * eW1[h];
  float ebase = eb1[0];
  for (int q = 0; q < 32; ++q) ebase += eW1[q];  // uniform, init-only

  // Rolling z-window (uniform scalars), seeded from x0's z-part:
  // wa/wb = past (A,B) pairs oldest->newest, uw = past u oldest->newest.
  const float* xz = x0 + e * 15;
  float wa0 = xz[3], wb0 = xz[4], wa1 = xz[5], wb1 = xz[6];
  float wa2 = xz[7], wb2 = xz[8], wa3 = xz[9], wb3 = xz[10];
  float uw0 = xz[11], uw1 = xz[12], uw2 = xz[13], uw3 = xz[14];

  const float* up = useq + e * TT;
  float* op = out + (size_t)e * TT * 4;

#define STAGE(SS, KK)                                                     \
  {                                                                       \
    float rv = __builtin_amdgcn_rcpf(                                     \
        __builtin_amdgcn_exp2f(fmaf(w0s, (SS), b0s)) + 1.0f);             \
    float q = sum16(wn * rv);                                             \
    float m1 = bcast15(q);                                                \
    float P3 = rdlane(q, 32);                                             \
    float t_ = fmaf(-0.1f, (SS), cstS);                                   \
    t_ = fmaf(aOwn, q, t_);                                               \
    t_ = fmaf(aM1, m1, t_);                                               \
    KK = fmaf(aR, P3, t_);                                                \
  }

#define STEP(UQ, SC_)                                                     \
  {                                                                       \
    const float cstS = fmaf(uco, (UQ), cstBase);                          \
    SC_ = S;                                                              \
    float k1, k2, k3, k4;                                                 \
    STAGE(S, k1)                                                          \
    float s2 = fmaf(0.5f, k1, S);                                         \
    STAGE(s2, k2)                                                         \
    float s3 = fmaf(0.5f, k2, S);                                         \
    STAGE(s3, k3)                                                         \
    float s4 = S + k3;                                                    \
    STAGE(s4, k4)                                                         \
    S = fmaf(1.0f / 6.0f, fmaf(2.0f, k2 + k3, k1) + k4, S);               \
  }

// estC pass: z = [A hist x4, B hist x4 interleaved via ew pairs, u hist x4].
#define EPASS(A0, A1, A2, A3, B0, B1, B2, B3, U0, U1, U2, U3, EST)        \
  {                                                                       \
    float acc = ebv;                                                      \
    acc = fmaf((A0), ew0, acc);  acc = fmaf((B0), ew1, acc);              \
    acc = fmaf((A1), ew2, acc);  acc = fmaf((B1), ew3, acc);              \
    acc = fmaf((A2), ew4, acc);  acc = fmaf((B2), ew5, acc);              \
    acc = fmaf((A3), ew6, acc);  acc = fmaf((B3), ew7, acc);              \
    acc = fmaf((U0), ew8, acc);  acc = fmaf((U1), ew9, acc);              \
    acc = fmaf((U2), ew10, acc); acc = fmaf((U3), ew11, acc);             \
    float rv = __builtin_amdgcn_rcpf(__builtin_amdgcn_exp2f(acc) + 1.0f); \
    float wv = ewn * rv;                                                  \
    wv = sum16(wv);                                                       \
    wv = wv + bcast15(wv); /* rows 1 & 3 now hold the 32-wide total */    \
    EST = wv + ebase;                                                     \
  }

  float uc0, uc1, uc2, uc3, uc4, uc5, uc6, uc7;
  {
    float4 a = *(const float4*)(up);
    float4 b = *(const float4*)(up + 4);
    uc0 = a.x; uc1 = a.y; uc2 = a.z; uc3 = a.w;
    uc4 = b.x; uc5 = b.y; uc6 = b.z; uc7 = b.w;
  }

  for (int t0 = 0; t0 < TT; t0 += K1) {
    const int tn = (t0 + K1 <= TT - K1) ? (t0 + K1) : (TT - K1);
    const float4 na = *(const float4*)(up + tn);
    const float4 nb = *(const float4*)(up + tn + 4);

    float sc0, sc1, sc2, sc3, sc4, sc5, sc6, sc7;
    STEP(uc0, sc0)
    STEP(uc1, sc1)
    STEP(uc2, sc2)
    STEP(uc3, sc3)
    STEP(uc4, sc4)
    STEP(uc5, sc5)
    STEP(uc6, sc6)
    STEP(uc7, sc7)

    // Broadcast this chunk's A (lane 0) and B (lane 16) states.
    const float bA0 = rdlane(sc0, 0), bB0 = rdlane(sc0, 16);
    const float bA1 = rdlane(sc1, 0), bB1 = rdlane(sc1, 16);
    const float bA2 = rdlane(sc2, 0), bB2 = rdlane(sc2, 16);
    const float bA3 = rdlane(sc3, 0), bB3 = rdlane(sc3, 16);
    const float bA4 = rdlane(sc4, 0), bB4 = rdlane(sc4, 16);
    const float bA5 = rdlane(sc5, 0), bB5 = rdlane(sc5, 16);
    const float bA6 = rdlane(sc6, 0), bB6 = rdlane(sc6, 16);
    const float bA7 = rdlane(sc7, 0), bB7 = rdlane(sc7, 16);

    float est0, est1, est2, est3, est4, est5, est6, est7;
    EPASS(wa0, wa1, wa2, wa3, wb0, wb1, wb2, wb3, uw0, uw1, uw2, uw3, est0)
    EPASS(wa1, wa2, wa3, bA0, wb1, wb2, wb3, bB0, uw1, uw2, uw3, uc0, est1)
    EPASS(wa2, wa3, bA0, bA1, wb2, wb3, bB0, bB1, uw2, uw3, uc0, uc1, est2)
    EPASS(wa3, bA0, bA1, bA2, wb3, bB0, bB1, bB2, uw3, uc0, uc1, uc2, est3)
    EPASS(bA0, bA1, bA2, bA3, bB0, bB1, bB2, bB3, uc0, uc1, uc2, uc3, est4)
    EPASS(bA1, bA2, bA3, bA4, bB1, bB2, bB3, bB4, uc1, uc2, uc3, uc4, est5)
    EPASS(bA2, bA3, bA4, bA5, bB2, bB3, bB4, bB5, uc2, uc3, uc4, uc5, est6)
    EPASS(bA3, bA4, bA5, bA6, bB3, bB4, bB5, bB6, uc3, uc4, uc5, uc6, est7)

    // Coalesced stores: lanes 0/16/32/48 write comps 0/1/2/3 of each 16B line.
    if (j == 0) {
      float* p = op + t0 * 4 + row;  // comp == row
      const bool isE = (row == 3);   // row3 stores estC (total also on row3)
      p[0]  = isE ? est0 : sc0;
      p[4]  = isE ? est1 : sc1;
      p[8]  = isE ? est2 : sc2;
      p[12] = isE ? est3 : sc3;
      p[16] = isE ? est4 : sc4;
      p[20] = isE ? est5 : sc5;
      p[24] = isE ? est6 : sc6;
      p[28] = isE ? est7 : sc7;
    }

    // Roll the z-window (before uc is overwritten).
    wa0 = bA4; wa1 = bA5; wa2 = bA6; wa3 = bA7;
    wb0 = bB4; wb1 = bB5; wb2 = bB6; wb3 = bB7;
    uw0 = uc4; uw1 = uc5; uw2 = uc6; uw3 = uc7;

    uc0 = na.x; uc1 = na.y; uc2 = na.z; uc3 = na.w;
    uc4 = nb.x; uc5 = nb.y; uc6 = nb.z; uc7 = nb.w;
  }
#undef STEP
#undef STAGE
#undef EPASS
}

// ---------------------------------------------------------------------------
extern "C" void kernel_launch(void* const* d_in, const int* in_sizes, int n_in,
                              void* d_out, int out_size, void* d_ws,
                              size_t ws_size, hipStream_t stream) {
  const float* useq = (const float*)d_in[0];
  const float* x0 = (const float*)d_in[1];
  float* out = (float*)d_out;

  fused_kernel<<<BB / 4, 256, 0, stream>>>(
      useq, x0,
      (const float*)d_in[2], (const float*)d_in[3], (const float*)d_in[4],
      (const float*)d_in[5], (const float*)d_in[6], (const float*)d_in[7],
      (const float*)d_in[8], (const float*)d_in[9], (const float*)d_in[10],
      (const float*)d_in[11], (const float*)d_in[12], (const float*)d_in[13],
      (const float*)d_in[14], (const float*)d_in[15], (const float*)d_in[16],
      (const float*)d_in[17], out);
}

// Round 8
// 500.232 us; speedup vs baseline: 1.0175x; 1.0175x over previous
//
#include <hip/hip_runtime.h>

#define TT 1024
#define BB 2048
#define K1 8
#define L2E2 2.8853900817779268f  // 2*log2(e)

// DPP helpers ----------------------------------------------------------------
template <int CTRL>
__device__ __forceinline__ float dpp_add(float x) {
  int y = __builtin_amdgcn_update_dpp(0, __float_as_int(x), CTRL, 0xF, 0xF, true);
  return x + __int_as_float(y);
}
// Sum within each aligned 16-lane row; result replicated in all 16 lanes.
__device__ __forceinline__ float sum16(float x) {
  x = dpp_add<0xB1>(x);   // quad_perm xor1
  x = dpp_add<0x4E>(x);   // quad_perm xor2
  x = dpp_add<0x141>(x);  // row_half_mirror
  x = dpp_add<0x140>(x);  // row_mirror
  return x;
}
// ROW_BCAST15: row r gets last lane of row r-1 (row0 -> 0).
__device__ __forceinline__ float bcast15(float x) {
  return __int_as_float(
      __builtin_amdgcn_update_dpp(0, __float_as_int(x), 0x142, 0xF, 0xF, true));
}
__device__ __forceinline__ float rdlane(float x, int l) {
  return __int_as_float(__builtin_amdgcn_readlane(__float_as_int(x), l));
}

// ---------------------------------------------------------------------------
// Fused RK4 scan + estC head. ONE element per 64-lane wave, 2048 waves =
// 2 waves/SIMD. __launch_bounds__(256,2): we launch exactly 2 waves/SIMD, so
// let the allocator use up to 256 VGPRs instead of starving at 28 and
// spending VALU issue on register recycling.
// Rows: row0=NN1/A, row1=NN2/B, row2=NN3/C, row3=NN3dup/Cdup.
// RK4 stage: one eval stream, sum16, one bcast15 (row1<-P1, row2<-P2),
// one readlane (P3 -> row1):
//   row0: KA = -0.1A + (0.2-C1) + 0.1u - P1(own)
//   row1: KB = -0.1B + cbC - 3P2(own) + (5/3)P1(m1) + P3(rdlane)
//   row2: KC = -0.1C + ccC -  P3(own) +       P2(m1)
// estC per 8-step chunk: A/B history broadcast via readlane (lanes 0/16),
// u history lane-uniform; t<4 edge seeded from x0's z-part into a rolling
// window. estC output bias folded into the (lane&31)==0 contribution.
__global__ __launch_bounds__(256, 2) void fused_kernel(
    const float* __restrict__ useq, const float* __restrict__ x0,
    const float* __restrict__ r1W0, const float* __restrict__ r1b0,
    const float* __restrict__ r1W1, const float* __restrict__ r1b1,
    const float* __restrict__ r2W0, const float* __restrict__ r2b0,
    const float* __restrict__ r2W1, const float* __restrict__ r2b1,
    const float* __restrict__ r3W0, const float* __restrict__ r3b0,
    const float* __restrict__ r3W1, const float* __restrict__ r3b1,
    const float* __restrict__ eW0, const float* __restrict__ eb0,
    const float* __restrict__ eW1, const float* __restrict__ eb1,
    float* __restrict__ out) {
  const int lane = threadIdx.x & 63;
  const int row = lane >> 4;
  const int j = lane & 15;
  const int e =
      __builtin_amdgcn_readfirstlane(blockIdx.x * 4 + (threadIdx.x >> 6));

  // RK4 per-lane weights (rows 2,3 share NN3).
  const float* W0p = (row == 0) ? r1W0 : (row == 1) ? r2W0 : r3W0;
  const float* b0p = (row == 0) ? r1b0 : (row == 1) ? r2b0 : r3b0;
  const float* W1p = (row == 0) ? r1W1 : (row == 1) ? r2W1 : r3W1;
  const float w0s = W0p[j] * L2E2;
  const float b0s = b0p[j] * L2E2;
  const float wn = -2.0f * W1p[j];

  // C_i = b1_i + sum_j W1_i[j]  (uniform, init-only).
  float C1 = r1b1[0], C2 = r2b1[0], C3 = r3b1[0];
  for (int q = 0; q < 16; ++q) {
    C1 += r1W1[q]; C2 += r2W1[q]; C3 += r3W1[q];
  }
  const float caC = 0.2f - C1;
  const float cbC = -1.0f / 6.0f + (5.0f / 3.0f) * C1 - 3.0f * C2 + C3;
  const float ccC = -1.0f / 6.0f + C2 - C3;

  // Per-lane combine coefficients.
  const float cstBase = (row == 0) ? caC : (row == 1) ? cbC : ccC;
  const float uco = (row == 0) ? 0.1f : 0.0f;
  const float aOwn = (row == 1) ? -3.0f : -1.0f;
  const float aM1 = (row == 0) ? 0.0f : (row == 1) ? (5.0f / 3.0f) : 1.0f;
  const float aR = (row == 1) ? 1.0f : 0.0f;

  float S = x0[e * 15 + ((row == 0) ? 0 : (row == 1) ? 1 : 2)];

  // estC per-lane weights: hidden unit h = lane & 31 (upper half duplicates).
  const int h = lane & 31;
  float ew0 = eW0[0 * 32 + h] * L2E2, ew1 = eW0[1 * 32 + h] * L2E2;
  float ew2 = eW0[2 * 32 + h] * L2E2, ew3 = eW0[3 * 32 + h] * L2E2;
  float ew4 = eW0[4 * 32 + h] * L2E2, ew5 = eW0[5 * 32 + h] * L2E2;
  float ew6 = eW0[6 * 32 + h] * L2E2, ew7 = eW0[7 * 32 + h] * L2E2;
  float ew8 = eW0[8 * 32 + h] * L2E2, ew9 = eW0[9 * 32 + h] * L2E2;
  float ew10 = eW0[10 * 32 + h] * L2E2, ew11 = eW0[11 * 32 + h] * L2E2;
  const float ebv = eb0[h] * L2E2;
  const float ewn = -2.0f * eW1[h];
  float ebase = eb1[0];
  for (int q = 0; q < 32; ++q) ebase += eW1[q];  // uniform, init-only
  // Fold output bias into the (h==0) lanes' pre-reduction contribution.
  const float ebL = (h == 0) ? ebase : 0.0f;

  // Rolling z-window (uniform scalars), seeded from x0's z-part.
  const float* xz = x0 + e * 15;
  float wa0 = xz[3], wb0 = xz[4], wa1 = xz[5], wb1 = xz[6];
  float wa2 = xz[7], wb2 = xz[8], wa3 = xz[9], wb3 = xz[10];
  float uw0 = xz[11], uw1 = xz[12], uw2 = xz[13], uw3 = xz[14];

  const float* up = useq + e * TT;
  float* op = out + (size_t)e * TT * 4;

#define STAGE(SS, KK)                                                     \
  {                                                                       \
    float rv = __builtin_amdgcn_rcpf(                                     \
        __builtin_amdgcn_exp2f(fmaf(w0s, (SS), b0s)) + 1.0f);             \
    float q = sum16(wn * rv);                                             \
    float m1 = bcast15(q);                                                \
    float P3 = rdlane(q, 32);                                             \
    float t_ = fmaf(-0.1f, (SS), cstS);                                   \
    t_ = fmaf(aOwn, q, t_);                                               \
    t_ = fmaf(aM1, m1, t_);                                               \
    KK = fmaf(aR, P3, t_);                                                \
  }

#define STEP(UQ, SC_)                                                     \
  {                                                                       \
    const float cstS = fmaf(uco, (UQ), cstBase);                          \
    SC_ = S;                                                              \
    float k1, k2, k3, k4;                                                 \
    STAGE(S, k1)                                                          \
    float s2 = fmaf(0.5f, k1, S);                                         \
    STAGE(s2, k2)                                                         \
    float s3 = fmaf(0.5f, k2, S);                                         \
    STAGE(s3, k3)                                                         \
    float s4 = S + k3;                                                    \
    STAGE(s4, k4)                                                         \
    S = fmaf(1.0f / 6.0f, fmaf(2.0f, k2 + k3, k1) + k4, S);               \
  }

// estC pass; EST valid on rows 1 & 3 (32-wide total incl. folded bias).
#define EPASS(A0, A1, A2, A3, B0, B1, B2, B3, U0, U1, U2, U3, EST)        \
  {                                                                       \
    float acc = ebv;                                                      \
    acc = fmaf((A0), ew0, acc);  acc = fmaf((B0), ew1, acc);              \
    acc = fmaf((A1), ew2, acc);  acc = fmaf((B1), ew3, acc);              \
    acc = fmaf((A2), ew4, acc);  acc = fmaf((B2), ew5, acc);              \
    acc = fmaf((A3), ew6, acc);  acc = fmaf((B3), ew7, acc);              \
    acc = fmaf((U0), ew8, acc);  acc = fmaf((U1), ew9, acc);              \
    acc = fmaf((U2), ew10, acc); acc = fmaf((U3), ew11, acc);             \
    float rv = __builtin_amdgcn_rcpf(__builtin_amdgcn_exp2f(acc) + 1.0f); \
    float wv = fmaf(ewn, rv, ebL);                                        \
    wv = sum16(wv);                                                       \
    EST = wv + bcast15(wv);                                               \
  }

  float uc0, uc1, uc2, uc3, uc4, uc5, uc6, uc7;
  {
    float4 a = *(const float4*)(up);
    float4 b = *(const float4*)(up + 4);
    uc0 = a.x; uc1 = a.y; uc2 = a.z; uc3 = a.w;
    uc4 = b.x; uc5 = b.y; uc6 = b.z; uc7 = b.w;
  }

  for (int t0 = 0; t0 < TT; t0 += K1) {
    const int tn = (t0 + K1 <= TT - K1) ? (t0 + K1) : (TT - K1);
    const float4 na = *(const float4*)(up + tn);
    const float4 nb = *(const float4*)(up + tn + 4);

    float sc0, sc1, sc2, sc3, sc4, sc5, sc6, sc7;
    STEP(uc0, sc0)
    STEP(uc1, sc1)
    STEP(uc2, sc2)
    STEP(uc3, sc3)
    STEP(uc4, sc4)
    STEP(uc5, sc5)
    STEP(uc6, sc6)
    STEP(uc7, sc7)

    // Broadcast this chunk's A (lane 0) and B (lane 16) states.
    const float bA0 = rdlane(sc0, 0), bB0 = rdlane(sc0, 16);
    const float bA1 = rdlane(sc1, 0), bB1 = rdlane(sc1, 16);
    const float bA2 = rdlane(sc2, 0), bB2 = rdlane(sc2, 16);
    const float bA3 = rdlane(sc3, 0), bB3 = rdlane(sc3, 16);
    const float bA4 = rdlane(sc4, 0), bB4 = rdlane(sc4, 16);
    const float bA5 = rdlane(sc5, 0), bB5 = rdlane(sc5, 16);
    const float bA6 = rdlane(sc6, 0), bB6 = rdlane(sc6, 16);
    const float bA7 = rdlane(sc7, 0), bB7 = rdlane(sc7, 16);

    float est0, est1, est2, est3, est4, est5, est6, est7;
    EPASS(wa0, wa1, wa2, wa3, wb0, wb1, wb2, wb3, uw0, uw1, uw2, uw3, est0)
    EPASS(wa1, wa2, wa3, bA0, wb1, wb2, wb3, bB0, uw1, uw2, uw3, uc0, est1)
    EPASS(wa2, wa3, bA0, bA1, wb2, wb3, bB0, bB1, uw2, uw3, uc0, uc1, est2)
    EPASS(wa3, bA0, bA1, bA2, wb3, bB0, bB1, bB2, uw3, uc0, uc1, uc2, est3)
    EPASS(bA0, bA1, bA2, bA3, bB0, bB1, bB2, bB3, uc0, uc1, uc2, uc3, est4)
    EPASS(bA1, bA2, bA3, bA4, bB1, bB2, bB3, bB4, uc1, uc2, uc3, uc4, est5)
    EPASS(bA2, bA3, bA4, bA5, bB2, bB3, bB4, bB5, uc2, uc3, uc4, uc5, est6)
    EPASS(bA3, bA4, bA5, bA6, bB3, bB4, bB5, bB6, uc3, uc4, uc5, uc6, est7)

    // Coalesced stores: lanes 0/16/32/48 write comps 0/1/2/3 of each 16B line.
    if (j == 0) {
      float* p = op + t0 * 4 + row;  // comp == row
      const bool isE = (row == 3);   // row3 stores estC
      p[0]  = isE ? est0 : sc0;
      p[4]  = isE ? est1 : sc1;
      p[8]  = isE ? est2 : sc2;
      p[12] = isE ? est3 : sc3;
      p[16] = isE ? est4 : sc4;
      p[20] = isE ? est5 : sc5;
      p[24] = isE ? est6 : sc6;
      p[28] = isE ? est7 : sc7;
    }

    // Roll the z-window (before uc is overwritten).
    wa0 = bA4; wa1 = bA5; wa2 = bA6; wa3 = bA7;
    wb0 = bB4; wb1 = bB5; wb2 = bB6; wb3 = bB7;
    uw0 = uc4; uw1 = uc5; uw2 = uc6; uw3 = uc7;

    uc0 = na.x; uc1 = na.y; uc2 = na.z; uc3 = na.w;
    uc4 = nb.x; uc5 = nb.y; uc6 = nb.z; uc7 = nb.w;
  }
#undef STEP
#undef STAGE
#undef EPASS
}

// ---------------------------------------------------------------------------
extern "C" void kernel_launch(void* const* d_in, const int* in_sizes, int n_in,
                              void* d_out, int out_size, void* d_ws,
                              size_t ws_size, hipStream_t stream) {
  const float* useq = (const float*)d_in[0];
  const float* x0 = (const float*)d_in[1];
  float* out = (float*)d_out;

  fused_kernel<<<BB / 4, 256, 0, stream>>>(
      useq, x0,
      (const float*)d_in[2], (const float*)d_in[3], (const float*)d_in[4],
      (const float*)d_in[5], (const float*)d_in[6], (const float*)d_in[7],
      (const float*)d_in[8], (const float*)d_in[9], (const float*)d_in[10],
      (const float*)d_in[11], (const float*)d_in[12], (const float*)d_in[13],
      (const float*)d_in[14], (const float*)d_in[15], (const float*)d_in[16],
      (const float*)d_in[17], out);
}